// Round 1
// baseline (860.299 us; speedup 1.0000x reference)
//
#include <hip/hip_runtime.h>

#define DIM   33
#define DIM2  (DIM*DIM)        // 1089
#define DIM3  (DIM*DIM*DIM)    // 35937
#define HW    (1080*1920)      // 2,073,600 pixels per plane
#define NIMG  16
#define GPI   (HW/4)           // 518,400 float4 groups per plane
#define TOTAL_GROUPS (NIMG*GPI)  // 8,294,400

typedef _Float16 half8 __attribute__((ext_vector_type(8)));
typedef float    f4    __attribute__((ext_vector_type(4)));

__device__ __forceinline__ float lerpf(float a, float b, float t) {
    return fmaf(t, b - a, a);
}

// ---------------------------------------------------------------------------
// Build packed LUT: for each cell (b,g,r) store 8 corners x 3 channels as fp16
// in one 64B-aligned 64B cell (48B data + 16B pad).
// layout: h[((db*2+dg)*2+dr)*3 + c]
// ---------------------------------------------------------------------------
__global__ void build_lut_kernel(const float* __restrict__ lut,
                                 half8* __restrict__ ws) {
    int cell = blockIdx.x * blockDim.x + threadIdx.x;
    if (cell >= DIM3) return;
    int b   = cell / DIM2;
    int rem = cell - b * DIM2;
    int g   = rem / DIM;
    int r   = rem - g * DIM;
    int bs[2] = { b, min(b + 1, DIM - 1) };
    int gs[2] = { g, min(g + 1, DIM - 1) };
    int rs[2] = { r, min(r + 1, DIM - 1) };

    _Float16 h[32];
#pragma unroll
    for (int i = 24; i < 32; ++i) h[i] = (_Float16)0.0f;
#pragma unroll
    for (int db = 0; db < 2; ++db)
#pragma unroll
        for (int dg = 0; dg < 2; ++dg)
#pragma unroll
            for (int dr = 0; dr < 2; ++dr) {
                int base = bs[db] * DIM2 + gs[dg] * DIM + rs[dr];
#pragma unroll
                for (int c = 0; c < 3; ++c)
                    h[((db * 2 + dg) * 2 + dr) * 3 + c] =
                        (_Float16)lut[c * DIM3 + base];
            }

    half8* dst = ws + (size_t)cell * 4;
#pragma unroll
    for (int q = 0; q < 4; ++q) {
        half8 v;
#pragma unroll
        for (int i = 0; i < 8; ++i) v[i] = h[q * 8 + i];
        dst[q] = v;
    }
}

// ---------------------------------------------------------------------------
// Main kernel: 4 pixels per thread (float4 plane loads/stores, non-temporal),
// one 64B packed cell per pixel (3 x dwordx4 gathers, single cache line).
// ---------------------------------------------------------------------------
__global__ __launch_bounds__(256) void lut3d_kernel(
        const float* __restrict__ x,
        const half8* __restrict__ tab,
        float* __restrict__ out) {
    int tid = blockIdx.x * blockDim.x + threadIdx.x;
    if (tid >= TOTAL_GROUPS) return;

    const float kInvBin = (float)(32.0 / 1.000001);

    int n = tid / GPI;
    int j = tid - n * GPI;

    const f4* xin = (const f4*)(x + (size_t)n * 3 * HW) + j;
    f4 r4 = __builtin_nontemporal_load(xin);
    f4 g4 = __builtin_nontemporal_load(xin + GPI);
    f4 b4 = __builtin_nontemporal_load(xin + 2 * GPI);

    f4 o0, o1, o2;
#pragma unroll
    for (int e = 0; e < 4; ++e) {
        float tr = r4[e] * kInvBin;
        float tg = g4[e] * kInvBin;
        float tb = b4[e] * kInvBin;
        float flr = floorf(tr), flg = floorf(tg), flb = floorf(tb);
        float dr = tr - flr, dg = tg - flg, db = tb - flb;
        int ir = (int)flr, ig = (int)flg, ib = (int)flb;
        ir = min(max(ir, 0), DIM - 2);
        ig = min(max(ig, 0), DIM - 2);
        ib = min(max(ib, 0), DIM - 2);

        int cell = (ib * DIM + ig) * DIM + ir;
        const half8* p = tab + (size_t)cell * 4;
        half8 q0 = p[0];
        half8 q1 = p[1];
        half8 q2 = p[2];

        float v[24];
#pragma unroll
        for (int i = 0; i < 8; ++i) {
            v[i]      = (float)q0[i];
            v[8 + i]  = (float)q1[i];
            v[16 + i] = (float)q2[i];
        }

        float res[3];
#pragma unroll
        for (int c = 0; c < 3; ++c) {
            float a00 = lerpf(v[c],      v[3 + c],  dr);   // (b0,g0)
            float a01 = lerpf(v[6 + c],  v[9 + c],  dr);   // (b0,g1)
            float a10 = lerpf(v[12 + c], v[15 + c], dr);   // (b1,g0)
            float a11 = lerpf(v[18 + c], v[21 + c], dr);   // (b1,g1)
            float c0  = lerpf(a00, a01, dg);
            float c1  = lerpf(a10, a11, dg);
            res[c]    = lerpf(c0, c1, db);
        }
        o0[e] = res[0];
        o1[e] = res[1];
        o2[e] = res[2];
    }

    f4* op = (f4*)(out + (size_t)n * 3 * HW) + j;
    __builtin_nontemporal_store(o0, op);
    __builtin_nontemporal_store(o1, op + GPI);
    __builtin_nontemporal_store(o2, op + 2 * GPI);
}

// ---------------------------------------------------------------------------
// Fallback (only if ws too small): direct fp32 gathers, one pixel per thread.
// ---------------------------------------------------------------------------
__global__ void lut3d_fallback_kernel(const float* __restrict__ x,
                                      const float* __restrict__ lut,
                                      float* __restrict__ out) {
    long long tid = (long long)blockIdx.x * blockDim.x + threadIdx.x;
    if (tid >= (long long)NIMG * HW) return;
    const float kInvBin = (float)(32.0 / 1.000001);
    int n = (int)(tid / HW);
    int p = (int)(tid - (long long)n * HW);
    const float* xb = x + (size_t)n * 3 * HW;
    float r = xb[p], g = xb[HW + p], b = xb[2 * HW + p];
    float tr = r * kInvBin, tg = g * kInvBin, tb = b * kInvBin;
    float flr = floorf(tr), flg = floorf(tg), flb = floorf(tb);
    float dr = tr - flr, dg = tg - flg, db = tb - flb;
    int ir = min(max((int)flr, 0), DIM - 2);
    int ig = min(max((int)flg, 0), DIM - 2);
    int ib = min(max((int)flb, 0), DIM - 2);
    float* ob = out + (size_t)n * 3 * HW;
#pragma unroll
    for (int c = 0; c < 3; ++c) {
        const float* L = lut + (size_t)c * DIM3;
        int base = ib * DIM2 + ig * DIM + ir;
        float v000 = L[base],               v100 = L[base + 1];
        float v010 = L[base + DIM],         v110 = L[base + DIM + 1];
        float v001 = L[base + DIM2],        v101 = L[base + DIM2 + 1];
        float v011 = L[base + DIM2 + DIM],  v111 = L[base + DIM2 + DIM + 1];
        float a00 = lerpf(v000, v100, dr);
        float a01 = lerpf(v010, v110, dr);
        float a10 = lerpf(v001, v101, dr);
        float a11 = lerpf(v011, v111, dr);
        float c0 = lerpf(a00, a01, dg);
        float c1 = lerpf(a10, a11, dg);
        ob[(size_t)c * HW + p] = lerpf(c0, c1, db);
    }
}

extern "C" void kernel_launch(void* const* d_in, const int* in_sizes, int n_in,
                              void* d_out, int out_size, void* d_ws, size_t ws_size,
                              hipStream_t stream) {
    const float* lut = (const float*)d_in[0];
    const float* x   = (const float*)d_in[1];
    float*       out = (float*)d_out;

    const size_t ws_needed = (size_t)DIM3 * 64;
    if (ws_size >= ws_needed) {
        hipLaunchKernelGGL(build_lut_kernel,
                           dim3((DIM3 + 255) / 256), dim3(256), 0, stream,
                           lut, (half8*)d_ws);
        hipLaunchKernelGGL(lut3d_kernel,
                           dim3(TOTAL_GROUPS / 256), dim3(256), 0, stream,
                           x, (const half8*)d_ws, out);
    } else {
        long long total = (long long)NIMG * HW;
        hipLaunchKernelGGL(lut3d_fallback_kernel,
                           dim3((unsigned)((total + 255) / 256)), dim3(256), 0, stream,
                           x, lut, out);
    }
}